// Round 7
// baseline (339.520 us; speedup 1.0000x reference)
//
#include <hip/hip_runtime.h>
#include <hip/hip_bf16.h>

#define NEG_SLOPE 0.2f

typedef short short8 __attribute__((ext_vector_type(8)));
typedef float floatx4 __attribute__((ext_vector_type(4)));
typedef unsigned short ushort8v __attribute__((ext_vector_type(8)));

__device__ __forceinline__ float bf2f_raw(unsigned short u) {
    union { float f; unsigned u; } c; c.u = ((unsigned)u) << 16; return c.f;
}
__device__ __forceinline__ unsigned short f2bf_raw(float f) {
    union { float f; unsigned u; } c; c.f = f;
    unsigned u = c.u;
    u += 0x7FFFu + ((u >> 16) & 1u);   // round-to-nearest-even
    return (unsigned short)(u >> 16);
}
__device__ __forceinline__ float ldf(const void* p, size_t i, int f32) {
    return f32 ? ((const float*)p)[i] : bf2f_raw(((const unsigned short*)p)[i]);
}
__device__ __forceinline__ unsigned short ldbf(const void* p, size_t i, int f32) {
    return f32 ? f2bf_raw(((const float*)p)[i]) : ((const unsigned short*)p)[i];
}
__device__ __forceinline__ int eidx(const void* edge, size_t i, int i64, int N) {
    long long v = i64 ? ((const long long*)edge)[i] : (long long)((const int*)edge)[i];
    if (v < 0) v = 0;
    if (v >= N) v = N - 1;
    return (int)v;
}
__device__ __forceinline__ float lrelu(float v) { return v > 0.f ? v : NEG_SLOPE * v; }

// K0: runtime dtype detection. flags[0]=x_is_f32, [1]=W_is_f32, [2]=att_is_f32, [3]=edge_is_i64
__global__ __launch_bounds__(256) void detect_kernel(
    const unsigned short* __restrict__ x, const unsigned short* __restrict__ W,
    const unsigned short* __restrict__ as_, const unsigned short* __restrict__ ad_,
    const unsigned* __restrict__ edge_w, int* __restrict__ flags, int edge_words)
{
    __shared__ float sm[256];
    __shared__ unsigned su[256];
    const int t = threadIdx.x;

    float mx = 0.f, mw = 0.f, ma = 0.f;
    for (int i = t; i < 4096; i += 256) {
        float v = fabsf(bf2f_raw(x[i]));
        mx = fmaxf(mx, (v == v && v < 3e38f) ? v : 1e9f);
    }
    for (int i = t; i < 4096; i += 256) {
        float v = fabsf(bf2f_raw(W[i]));
        mw = fmaxf(mw, (v == v && v < 3e38f) ? v : 1e9f);
    }
    {
        float v1 = fabsf(bf2f_raw(as_[t]));
        float v2 = fabsf(bf2f_raw(ad_[t]));
        v1 = (v1 == v1 && v1 < 3e38f) ? v1 : 1e9f;
        v2 = (v2 == v2 && v2 < 3e38f) ? v2 : 1e9f;
        ma = fmaxf(v1, v2);
    }
    unsigned ow = 0;
    {
        int i = 2 * t + 1;
        if (i < edge_words) ow = edge_w[i];
    }

    sm[t] = mx; __syncthreads();
    for (int s = 128; s; s >>= 1) { if (t < s) sm[t] = fmaxf(sm[t], sm[t + s]); __syncthreads(); }
    if (t == 0) flags[0] = sm[0] > 100.f;
    __syncthreads();

    sm[t] = mw; __syncthreads();
    for (int s = 128; s; s >>= 1) { if (t < s) sm[t] = fmaxf(sm[t], sm[t + s]); __syncthreads(); }
    if (t == 0) flags[1] = sm[0] > 100.f;
    __syncthreads();

    sm[t] = ma; __syncthreads();
    for (int s = 128; s; s >>= 1) { if (t < s) sm[t] = fmaxf(sm[t], sm[t + s]); __syncthreads(); }
    if (t == 0) flags[2] = sm[0] > 100.f;
    __syncthreads();

    su[t] = ow; __syncthreads();
    for (int s = 128; s; s >>= 1) { if (t < s) su[t] |= su[t + s]; __syncthreads(); }
    if (t == 0) flags[3] = (su[0] == 0u);
}

// K0b: pre-transpose W into MFMA B-fragment order (16B-coalesced fb loads).
__global__ __launch_bounds__(256) void wt_kernel(
    const void* __restrict__ W, unsigned short* __restrict__ Wt,
    const int* __restrict__ flags)
{
    int i = blockIdx.x * 256 + threadIdx.x;   // 65536 total
    int j = i & 7;
    int l = (i >> 3) & 63;
    int ks = (i >> 9) & 7;
    int c = i >> 12;
    int k = ks * 32 + (l >> 4) * 8 + j;
    int n = c * 16 + (l & 15);
    Wt[i] = ldbf(W, (size_t)k * 256 + n, flags[1]);
}

// K1: MFMA gemm, L2/L1-served W. Same HEAD for all 4 waves of a block so the
// per-tile fb reloads hit identical addresses -> L1-resident (round-6: 4 heads
// per block = 128KB fb working set >> 32KB L1, every iteration refetched L2).
__global__ __launch_bounds__(256) void gemm_mfma_kernel(
    const void* __restrict__ x, const unsigned short* __restrict__ Wt,
    const void* __restrict__ att_src, const void* __restrict__ att_dst,
    unsigned short* __restrict__ h_out, float* __restrict__ a_s, float* __restrict__ a_d,
    const int* __restrict__ flags, int N, int ntiles)
{
    const int head = blockIdx.x & 3;
    const int wslot = (blockIdx.x >> 2) * 4 + (threadIdx.x >> 6);
    const int nslots = (gridDim.x >> 2) * 4;
    const int l = threadIdx.x & 63;
    const int lane16 = l & 15;
    const int quad = l >> 4;
    const int xf = flags[0], af = flags[2];
    const int n0w = head * 64;

    float as_att[4], ad_att[4];
    #pragma unroll
    for (int nt = 0; nt < 4; ++nt) {
        as_att[nt] = ldf(att_src, n0w + nt * 16 + lane16, af);
        ad_att[nt] = ldf(att_dst, n0w + nt * 16 + lane16, af);
    }

    for (int tile = wslot; tile < ntiles; tile += nslots) {
        const int m0 = tile * 32;
        int r0 = m0 + lane16;      if (r0 >= N) r0 = N - 1;
        int r1 = m0 + 16 + lane16; if (r1 >= N) r1 = N - 1;

        short8 fa0[8], fa1[8];
        if (!xf) {
            const char* b0 = (const char*)x + ((size_t)r0 * 256 + quad * 8) * 2;
            const char* b1 = (const char*)x + ((size_t)r1 * 256 + quad * 8) * 2;
            #pragma unroll
            for (int ks = 0; ks < 8; ++ks) {
                fa0[ks] = *(const short8*)(b0 + ks * 64);
                fa1[ks] = *(const short8*)(b1 + ks * 64);
            }
        } else {
            const float* b0 = (const float*)x + (size_t)r0 * 256 + quad * 8;
            const float* b1 = (const float*)x + (size_t)r1 * 256 + quad * 8;
            #pragma unroll
            for (int ks = 0; ks < 8; ++ks) {
                #pragma unroll
                for (int j = 0; j < 8; ++j) {
                    fa0[ks][j] = (short)f2bf_raw(b0[ks * 32 + j]);
                    fa1[ks][j] = (short)f2bf_raw(b1[ks * 32 + j]);
                }
            }
        }

        floatx4 acc0[4], acc1[4];
        #pragma unroll
        for (int nt = 0; nt < 4; ++nt) {
            acc0[nt] = (floatx4){0.f, 0.f, 0.f, 0.f};
            acc1[nt] = (floatx4){0.f, 0.f, 0.f, 0.f};
        }

        const unsigned short* wp0 = Wt + (((size_t)head * 32) * 64 + l) * 8;
        #pragma unroll
        for (int ks = 0; ks < 8; ++ks) {
            const unsigned short* wp = wp0 + (size_t)ks * 512;
            #pragma unroll
            for (int nt = 0; nt < 4; ++nt) {
                short8 fb = *(const short8*)(wp + nt * 4096);
                acc0[nt] = __builtin_amdgcn_mfma_f32_16x16x32_bf16(fa0[ks], fb, acc0[nt], 0, 0, 0);
                acc1[nt] = __builtin_amdgcn_mfma_f32_16x16x32_bf16(fa1[ks], fb, acc1[nt], 0, 0, 0);
            }
        }

        #pragma unroll
        for (int st = 0; st < 2; ++st) {
            const floatx4* acc = st ? acc1 : acc0;
            const int mb = m0 + st * 16;
            #pragma unroll
            for (int nt = 0; nt < 4; ++nt) {
                const int col = n0w + nt * 16 + lane16;
                #pragma unroll
                for (int r = 0; r < 4; ++r) {
                    const int row = mb + quad * 4 + r;
                    if (row < N)
                        h_out[(size_t)row * 256 + col] = f2bf_raw(acc[nt][r]);
                }
            }
            #pragma unroll
            for (int r = 0; r < 4; ++r) {
                float vs = acc[0][r] * as_att[0] + acc[1][r] * as_att[1]
                         + acc[2][r] * as_att[2] + acc[3][r] * as_att[3];
                float vd = acc[0][r] * ad_att[0] + acc[1][r] * ad_att[1]
                         + acc[2][r] * ad_att[2] + acc[3][r] * ad_att[3];
                vs += __shfl_xor(vs, 1); vs += __shfl_xor(vs, 2);
                vs += __shfl_xor(vs, 4); vs += __shfl_xor(vs, 8);
                vd += __shfl_xor(vd, 1); vd += __shfl_xor(vd, 2);
                vd += __shfl_xor(vd, 4); vd += __shfl_xor(vd, 8);
                if (lane16 == 0) {
                    const int row = mb + quad * 4 + r;
                    if (row < N) {
                        a_s[row * 4 + head] = vs;
                        a_d[row * 4 + head] = vd;
                    }
                }
            }
        }
    }
}

// K3: count in-degree per dst.
__global__ __launch_bounds__(256) void count_kernel(
    const void* __restrict__ edge, int* __restrict__ deg,
    const int* __restrict__ flags, int E, int N)
{
    int e = blockIdx.x * 256 + threadIdx.x;
    if (e >= E) return;
    int d = eidx(edge, (size_t)E + e, flags[3], N);
    atomicAdd(&deg[d], 1);
}

// K4a: per-1024-chunk exclusive scan; block sums out.
__global__ __launch_bounds__(256) void scan1_kernel(
    const int* __restrict__ deg, int* __restrict__ row_off,
    int* __restrict__ blk_sum, int N)
{
    __shared__ int sh[256];
    const int b = blockIdx.x, t = threadIdx.x;
    const int base = b * 1024 + t * 4;
    int v[4], ts = 0;
    #pragma unroll
    for (int i = 0; i < 4; ++i) {
        int idx = base + i;
        v[i] = (idx < N) ? deg[idx] : 0;
        ts += v[i];
    }
    sh[t] = ts; __syncthreads();
    for (int off = 1; off < 256; off <<= 1) {
        int add = (t >= off) ? sh[t - off] : 0;
        __syncthreads();
        sh[t] += add;
        __syncthreads();
    }
    int run = sh[t] - ts;
    if (t == 255) blk_sum[b] = sh[255];
    #pragma unroll
    for (int i = 0; i < 4; ++i) {
        int idx = base + i;
        if (idx < N) row_off[idx] = run;
        run += v[i];
    }
}

// K4b: exclusive scan of block sums.
__global__ void scan2_kernel(int* __restrict__ blk_sum, int nb) {
    const int t = threadIdx.x;
    if (nb <= 64) {
        int orig = (t < nb) ? blk_sum[t] : 0;
        int v = orig;
        #pragma unroll
        for (int off = 1; off < 64; off <<= 1) {
            int u = __shfl_up(v, off);
            if (t >= off) v += u;
        }
        if (t < nb) blk_sum[t] = v - orig;
    } else if (t == 0) {
        int run = 0;
        for (int i = 0; i < nb; ++i) { int v = blk_sum[i]; blk_sum[i] = run; run += v; }
    }
}

// K4c: add block bases; init cursors.
__global__ __launch_bounds__(256) void scan3_kernel(
    int* __restrict__ row_off, const int* __restrict__ blk_sum,
    int* __restrict__ cursor, int N)
{
    int i = blockIdx.x * 256 + threadIdx.x;
    if (i < N) {
        int v = row_off[i] + blk_sum[i >> 10];
        row_off[i] = v;
        cursor[i] = v;
    }
}

// K5: scatter src indices into dst-sorted edge list.
__global__ __launch_bounds__(256) void scatter_kernel(
    const void* __restrict__ edge, int* __restrict__ cursor,
    int* __restrict__ elist, const int* __restrict__ flags, int E, int N)
{
    int e = blockIdx.x * 256 + threadIdx.x;
    if (e >= E) return;
    int i64 = flags[3];
    int s = eidx(edge, e, i64, N);
    int d = eidx(edge, (size_t)E + e, i64, N);
    int pos = atomicAdd(&cursor[d], 1);
    elist[pos] = s;
}

// K6: gather-aggregate, one WAVE per node, QUARTER-wave per edge:
// 16 lanes x 32B = 512B row; 4 edges in flight + depth-2 prefetch = ~8-12
// outstanding vmem per wave (round-6 had only 2 -> latency-bound at 47% HBM).
__global__ __launch_bounds__(256) void aggregate_kernel(
    const int* __restrict__ row_off, const int* __restrict__ deg,
    const int* __restrict__ elist,
    const float* __restrict__ a_s, const float* __restrict__ a_d,
    const unsigned short* __restrict__ h_ws,
    const void* __restrict__ bias, void* __restrict__ out,
    const int* __restrict__ flags, int N)
{
    const int n = blockIdx.x * 4 + (threadIdx.x >> 6);
    if (n >= N) return;
    const int lane = threadIdx.x & 63;
    const int q = lane >> 4;        // quarter: handles edges c0+q
    const int li = lane & 15;       // lane-in-quarter
    const int col0 = li * 16;       // 16 cols per lane
    const int head = li >> 2;       // col0/64

    const int dn = deg[n];
    const int row = row_off[n];
    const float adn = a_d[n * 4 + head];
    const float self_logit = lrelu(a_s[n * 4 + head] + adn);

    float acc[16];
    {
        ushort8v h0 = *(const ushort8v*)(h_ws + (size_t)n * 256 + col0);
        ushort8v h1 = *(const ushort8v*)(h_ws + (size_t)n * 256 + col0 + 8);
        #pragma unroll
        for (int j = 0; j < 8; ++j) {
            acc[j]     = (q == 0) ? bf2f_raw(h0[j]) : 0.f;
            acc[8 + j] = (q == 0) ? bf2f_raw(h1[j]) : 0.f;
        }
    }
    float ssum = (q == 0) ? 1.f : 0.f;

    // prologue: cur edge q, next edge 4+q
    bool v0 = q < dn;
    bool v1 = 4 + q < dn;
    int s0 = v0 ? elist[row + q] : n;
    int s1 = v1 ? elist[row + 4 + q] : n;
    float as0 = a_s[s0 * 4 + head];
    ushort8v a0 = *(const ushort8v*)(h_ws + (size_t)s0 * 256 + col0);
    ushort8v b0 = *(const ushort8v*)(h_ws + (size_t)s0 * 256 + col0 + 8);

    for (int c0 = 0; c0 < dn; c0 += 4) {
        const int e2 = c0 + 8 + q;
        const bool v2 = e2 < dn;
        const int s2 = v2 ? elist[row + e2] : n;
        const float as1 = a_s[s1 * 4 + head];
        const ushort8v a1 = *(const ushort8v*)(h_ws + (size_t)s1 * 256 + col0);
        const ushort8v b1 = *(const ushort8v*)(h_ws + (size_t)s1 * 256 + col0 + 8);

        const float p = v0 ? __expf(lrelu(as0 + adn) - self_logit) : 0.f;
        ssum += p;
        #pragma unroll
        for (int j = 0; j < 8; ++j) {
            acc[j]     += p * bf2f_raw(a0[j]);
            acc[8 + j] += p * bf2f_raw(b0[j]);
        }

        s0 = s1; as0 = as1; a0 = a1; b0 = b1; v0 = v1;
        s1 = s2; v1 = v2;
    }

    // combine the four quarters (each covers all 256 cols)
    #pragma unroll
    for (int j = 0; j < 16; ++j) {
        acc[j] += __shfl_xor(acc[j], 16);
        acc[j] += __shfl_xor(acc[j], 32);
    }
    ssum += __shfl_xor(ssum, 16);
    ssum += __shfl_xor(ssum, 32);

    if (q == 0) {
        const float inv = 1.f / ssum;
        const int bf32 = flags[2];
        float o[16];
        #pragma unroll
        for (int j = 0; j < 16; ++j)
            o[j] = acc[j] * inv + ldf(bias, col0 + j, bf32);
        if (flags[0]) {
            float* op = (float*)out + (size_t)n * 256 + col0;
            #pragma unroll
            for (int v = 0; v < 4; ++v)
                *(floatx4*)(op + v * 4) = (floatx4){o[v*4], o[v*4+1], o[v*4+2], o[v*4+3]};
        } else {
            ushort8v ov0, ov1;
            #pragma unroll
            for (int j = 0; j < 8; ++j) { ov0[j] = f2bf_raw(o[j]); ov1[j] = f2bf_raw(o[8 + j]); }
            unsigned short* op = (unsigned short*)out + (size_t)n * 256 + col0;
            *(ushort8v*)op       = ov0;
            *(ushort8v*)(op + 8) = ov1;
        }
    }
}

// Diagnostic: ws too small -> absmax tells us ws_MB*1000.
__global__ __launch_bounds__(256) void sentinel_kernel(unsigned short* out, size_t n, float v) {
    size_t i = (size_t)blockIdx.x * 256 + threadIdx.x;
    if (i < n) out[i] = f2bf_raw(v);
}

extern "C" void kernel_launch(void* const* d_in, const int* in_sizes, int n_in,
                              void* d_out, int out_size, void* d_ws, size_t ws_size,
                              hipStream_t stream) {
    const void* x       = d_in[0];
    const void* edge    = d_in[1];
    const void* W       = d_in[2];
    const void* att_src = d_in[3];
    const void* att_dst = d_in[4];
    const void* bias    = d_in[5];

    const int N = in_sizes[0] / 256;   // 50000
    const int E = in_sizes[1] / 2;     // 800000

    char* ws = (char*)d_ws;
    size_t off = 256;
    int*   flags   = (int*)ws;
    float* a_s     = (float*)(ws + off); off += (size_t)N * 4 * sizeof(float);
    float* a_d     = (float*)(ws + off); off += (size_t)N * 4 * sizeof(float);
    int*   deg     = (int*)(ws + off);   off += (size_t)N * sizeof(int);
    int*   row_off = (int*)(ws + off);   off += (size_t)N * sizeof(int);
    int*   cursor  = (int*)(ws + off);   off += (size_t)N * sizeof(int);
    int*   blk_sum = (int*)(ws + off);   off += 256 * sizeof(int);
    unsigned short* Wt = (unsigned short*)(ws + off); off += 65536 * sizeof(unsigned short);
    int*   elist   = (int*)(ws + off);   off += (size_t)E * sizeof(int);
    unsigned short* h_ws = (unsigned short*)(ws + off);
    const size_t need = off + (size_t)N * 256 * sizeof(unsigned short);

    if (ws_size < need) {
        float v = (float)(ws_size >> 20) * 1000.0f;
        size_t n = (size_t)out_size;
        sentinel_kernel<<<(unsigned)((n + 255) / 256), 256, 0, stream>>>(
            (unsigned short*)d_out, n, v);
        return;
    }

    int edge_words = (2 * E < 512) ? 2 * E : 512;
    detect_kernel<<<1, 256, 0, stream>>>(
        (const unsigned short*)x, (const unsigned short*)W,
        (const unsigned short*)att_src, (const unsigned short*)att_dst,
        (const unsigned*)edge, flags, edge_words);

    wt_kernel<<<256, 256, 0, stream>>>(W, Wt, flags);

    const int ntiles = (N + 31) / 32;
    const int nblocks = 512;
    gemm_mfma_kernel<<<nblocks, 256, 0, stream>>>(
        x, Wt, att_src, att_dst, h_ws, a_s, a_d, flags, N, ntiles);

    hipMemsetAsync(deg, 0, (size_t)N * sizeof(int), stream);
    count_kernel<<<(E + 255) / 256, 256, 0, stream>>>(edge, deg, flags, E, N);

    const int nb = (N + 1023) / 1024;
    scan1_kernel<<<nb, 256, 0, stream>>>(deg, row_off, blk_sum, N);
    scan2_kernel<<<1, 64, 0, stream>>>(blk_sum, nb);
    scan3_kernel<<<(N + 255) / 256, 256, 0, stream>>>(row_off, blk_sum, cursor, N);

    scatter_kernel<<<(E + 255) / 256, 256, 0, stream>>>(edge, cursor, elist, flags, E, N);

    aggregate_kernel<<<(N + 3) / 4, 256, 0, stream>>>(
        row_off, deg, elist, a_s, a_d, h_ws, bias, d_out, flags, N);
}